// Round 1
// baseline (289.037 us; speedup 1.0000x reference)
//
#include <hip/hip_runtime.h>
#include <math.h>

#define NUSER 100000
#define NITEM 50000
#define DIM_E 128
#define DIM_F 256
#define BATCH 1024
#define NCOL 128            /* 1 + NUM_NEG */
#define FLAT (BATCH * NCOL)

__device__ __forceinline__ float dot4(float4 a, float4 b) {
    return a.x * b.x + a.y * b.y + a.z * b.z + a.w * b.w;
}

__global__ __launch_bounds__(256) void zero_flags_kernel(int* __restrict__ flags) {
    int i = blockIdx.x * 256 + threadIdx.x;
    if (i < FLAT) flags[i] = 0;
}

__global__ __launch_bounds__(256) void scatter_flags_kernel(const int* __restrict__ ridx,
                                                            int n, int* __restrict__ flags) {
    int i = blockIdx.x * 256 + threadIdx.x;
    if (i < n) flags[ridx[i]] = 1;
}

// Fused item-feature MLP: feature = (l2norm(v_feat) @ W1 + b1).leaky_relu() @ W2 + b2
// 32 rows per block of 256 threads.
__global__ __launch_bounds__(256) void mlp_kernel(const float* __restrict__ vfeat,
                                                  const float* __restrict__ W1,
                                                  const float* __restrict__ b1,
                                                  const float* __restrict__ W2,
                                                  const float* __restrict__ b2,
                                                  float* __restrict__ featout) {
    __shared__ float As[32][260];
    __shared__ float Hs[32][260];
    __shared__ float invn[32];
    const int t = threadIdx.x;
    const int r0 = blockIdx.x * 32;

    // ---- load 32x256 input tile (float4, coalesced) ----
#pragma unroll
    for (int i = 0; i < 8; ++i) {
        int idx = t + i * 256;      // float4 index in [0, 2048)
        int r = idx >> 6;           // 64 float4 per row
        int c4 = idx & 63;
        float4 v = make_float4(0.f, 0.f, 0.f, 0.f);
        if (r0 + r < NITEM) v = *(const float4*)(vfeat + (size_t)(r0 + r) * DIM_F + c4 * 4);
        ((float4*)(&As[r][0]))[c4] = v;
    }
    __syncthreads();

    // ---- row inverse norms (8 threads per row) ----
    {
        int r = t >> 3, seg = t & 7;
        const float4* row4 = (const float4*)(&As[r][0]);
        float s = 0.f;
#pragma unroll
        for (int i = 0; i < 8; ++i) { float4 v = row4[seg * 8 + i]; s += dot4(v, v); }
        s += __shfl_down(s, 4, 8);
        s += __shfl_down(s, 2, 8);
        s += __shfl_down(s, 1, 8);
        if (seg == 0) invn[r] = 1.f / fmaxf(sqrtf(s), 1e-12f);
    }
    __syncthreads();

    const int wid = t >> 6;     // wave id 0..3
    const int lane = t & 63;
    const int rbase = wid * 8;  // each wave owns 8 rows in stage 1

    // ---- stage 1: H = leaky(invn * (A @ W1) + b1), cols lane*4..+3 ----
    {
        float acc[8][4];
#pragma unroll
        for (int a = 0; a < 8; ++a)
#pragma unroll
            for (int b = 0; b < 4; ++b) acc[a][b] = 0.f;

        for (int k4 = 0; k4 < 64; ++k4) {
            float4 w0 = *(const float4*)(W1 + (size_t)(k4 * 4 + 0) * 256 + lane * 4);
            float4 w1 = *(const float4*)(W1 + (size_t)(k4 * 4 + 1) * 256 + lane * 4);
            float4 w2 = *(const float4*)(W1 + (size_t)(k4 * 4 + 2) * 256 + lane * 4);
            float4 w3 = *(const float4*)(W1 + (size_t)(k4 * 4 + 3) * 256 + lane * 4);
#pragma unroll
            for (int rr = 0; rr < 8; ++rr) {
                float4 a = *(const float4*)(&As[rbase + rr][k4 * 4]);
                acc[rr][0] += a.x * w0.x + a.y * w1.x + a.z * w2.x + a.w * w3.x;
                acc[rr][1] += a.x * w0.y + a.y * w1.y + a.z * w2.y + a.w * w3.y;
                acc[rr][2] += a.x * w0.z + a.y * w1.z + a.z * w2.z + a.w * w3.z;
                acc[rr][3] += a.x * w0.w + a.y * w1.w + a.z * w2.w + a.w * w3.w;
            }
        }
        float4 bv = *(const float4*)(b1 + lane * 4);
#pragma unroll
        for (int rr = 0; rr < 8; ++rr) {
            float inv = invn[rbase + rr];
            float4 h;
            h.x = inv * acc[rr][0] + bv.x;
            h.y = inv * acc[rr][1] + bv.y;
            h.z = inv * acc[rr][2] + bv.z;
            h.w = inv * acc[rr][3] + bv.w;
            h.x = h.x > 0.f ? h.x : 0.01f * h.x;
            h.y = h.y > 0.f ? h.y : 0.01f * h.y;
            h.z = h.z > 0.f ? h.z : 0.01f * h.z;
            h.w = h.w > 0.f ? h.w : 0.01f * h.w;
            ((float4*)(&Hs[rbase + rr][0]))[lane] = h;
        }
    }
    __syncthreads();

    // ---- stage 2: feature = H @ W2 + b2 ----
    {
        const int j = t & 127;
        const int g = t >> 7;   // 0 or 1 -> rows g*16..+15
        float acc2[16];
#pragma unroll
        for (int rr = 0; rr < 16; ++rr) acc2[rr] = 0.f;

        for (int k4 = 0; k4 < 64; ++k4) {
            float w0 = W2[(size_t)(k4 * 4 + 0) * 128 + j];
            float w1 = W2[(size_t)(k4 * 4 + 1) * 128 + j];
            float w2v = W2[(size_t)(k4 * 4 + 2) * 128 + j];
            float w3 = W2[(size_t)(k4 * 4 + 3) * 128 + j];
#pragma unroll
            for (int rr = 0; rr < 16; ++rr) {
                float4 hv = *(const float4*)(&Hs[g * 16 + rr][k4 * 4]);
                acc2[rr] += hv.x * w0 + hv.y * w1 + hv.z * w2v + hv.w * w3;
            }
        }
        float bb = b2[j];
#pragma unroll
        for (int rr = 0; rr < 16; ++rr) {
            int r = r0 + g * 16 + rr;
            if (r < NITEM) featout[(size_t)r * DIM_E + j] = acc2[rr] + bb;
        }
    }
}

// One block per batch row (128 flat elements). 2 threads per element.
__global__ __launch_bounds__(256) void contrast_kernel(const int* __restrict__ user,
                                                       const int* __restrict__ item,
                                                       const int* __restrict__ flags,
                                                       const float* __restrict__ idemb,
                                                       const float* __restrict__ feat,
                                                       float* __restrict__ rowvals) {
    __shared__ float pe[128];           // normalized pos embedding
    __shared__ float s1s[128], s2s[128], rs[128];
    const int row = blockIdx.x;
    const int t = threadIdx.x;

    if (t < 32) {
        int p = item[(size_t)row * NCOL];  // item_tensor[row][0]
        float4 v = *(const float4*)(idemb + (size_t)p * DIM_E + t * 4);
        float s = dot4(v, v);
#pragma unroll
        for (int off = 16; off >= 1; off >>= 1) s += __shfl_xor(s, off, 32);
        float inv = 1.f / fmaxf(sqrtf(s), 1e-12f);
        *(float4*)(&pe[t * 4]) = make_float4(v.x * inv, v.y * inv, v.z * inv, v.w * inv);
    }
    __syncthreads();

    const int e = t >> 1;       // element 0..127
    const int h = t & 1;        // half of the 128-dim vector
    const size_t j = (size_t)row * NCOL + e;
    const int u = user[j];
    const int it = item[j];
    const int fl = flags[j];
    const float* up = idemb + (size_t)u * DIM_E + h * 64;
    const float* ip = idemb + (size_t)it * DIM_E + h * 64;
    const float* fp = feat + (size_t)(it - NUSER) * DIM_E + h * 64;

    float su = 0.f, si = 0.f, sf = 0.f, dpf = 0.f, dux = 0.f;
#pragma unroll
    for (int i = 0; i < 16; ++i) {
        float4 uv = ((const float4*)up)[i];
        float4 iv = ((const float4*)ip)[i];
        float4 fv = ((const float4*)fp)[i];
        float4 pv = *(const float4*)(&pe[h * 64 + i * 4]);
        su += dot4(uv, uv);
        si += dot4(iv, iv);
        sf += dot4(fv, fv);
        dpf += dot4(pv, fv);
        float4 xv = fl ? fv : iv;
        dux += dot4(uv, xv);
    }
    su += __shfl_xor(su, 1);
    si += __shfl_xor(si, 1);
    sf += __shfl_xor(sf, 1);
    dpf += __shfl_xor(dpf, 1);
    dux += __shfl_xor(dux, 1);

    if (h == 0) {
        float fnorm = fmaxf(sqrtf(sf), 1e-12f);
        float d1 = dpf / fnorm;                 // head_embed . head_feat
        s1s[e] = expf(d1 * 0.5f);               // / TEMP (=2)
        s2s[e] = expf(dux * 0.5f);
        rs[e] = sqrtf(su) + sqrtf(si);
    }
    __syncthreads();

    if (t < 64) {
        float a1 = s1s[t] + s1s[t + 64];
        float a2 = s2s[t] + s2s[t + 64];
        float a3 = rs[t] + rs[t + 64];
#pragma unroll
        for (int off = 32; off >= 1; off >>= 1) {
            a1 += __shfl_xor(a1, off);
            a2 += __shfl_xor(a2, off);
            a3 += __shfl_xor(a3, off);
        }
        if (t == 0) {
            rowvals[row * 4 + 0] = logf(a1) - logf(s1s[0]);
            rowvals[row * 4 + 1] = logf(a2) - logf(s2s[0]);
            rowvals[row * 4 + 2] = a3;
        }
    }
}

__global__ __launch_bounds__(256) void finalize_kernel(const float* __restrict__ rowvals,
                                                       float* __restrict__ out) {
    float c1 = 0.f, c2 = 0.f, rg = 0.f;
    for (int i = threadIdx.x; i < BATCH; i += 256) {
        c1 += rowvals[i * 4 + 0];
        c2 += rowvals[i * 4 + 1];
        rg += rowvals[i * 4 + 2];
    }
#pragma unroll
    for (int off = 32; off >= 1; off >>= 1) {
        c1 += __shfl_xor(c1, off);
        c2 += __shfl_xor(c2, off);
        rg += __shfl_xor(rg, off);
    }
    __shared__ float buf[4][3];
    int wid = threadIdx.x >> 6, lane = threadIdx.x & 63;
    if (lane == 0) { buf[wid][0] = c1; buf[wid][1] = c2; buf[wid][2] = rg; }
    __syncthreads();
    if (threadIdx.x == 0) {
        float C1 = buf[0][0] + buf[1][0] + buf[2][0] + buf[3][0];
        float C2 = buf[0][1] + buf[1][1] + buf[2][1] + buf[3][1];
        float R  = buf[0][2] + buf[1][2] + buf[2][2] + buf[3][2];
        out[0] = 0.5f * (C1 / (float)BATCH) + 0.5f * (C2 / (float)BATCH);
        out[1] = 0.5f * (R / (float)FLAT);
    }
}

extern "C" void kernel_launch(void* const* d_in, const int* in_sizes, int n_in,
                              void* d_out, int out_size, void* d_ws, size_t ws_size,
                              hipStream_t stream) {
    const int* user = (const int*)d_in[0];
    const int* item = (const int*)d_in[1];
    const int* ridx = (const int*)d_in[2];
    const float* idemb = (const float*)d_in[3];
    const float* vfeat = (const float*)d_in[4];
    const float* W1 = (const float*)d_in[5];
    const float* b1 = (const float*)d_in[6];
    const float* W2 = (const float*)d_in[7];
    const float* b2 = (const float*)d_in[8];
    float* out = (float*)d_out;

    char* ws = (char*)d_ws;
    float* feat = (float*)ws;                                   // 50000*128*4 = 25,600,000 B
    int* flags = (int*)(ws + 25600000);                         // 524,288 B
    float* rowvals = (float*)(ws + 25600000 + 524288);          // 16,384 B

    const int nridx = in_sizes[2];

    zero_flags_kernel<<<dim3((FLAT + 255) / 256), dim3(256), 0, stream>>>(flags);
    scatter_flags_kernel<<<dim3((nridx + 255) / 256), dim3(256), 0, stream>>>(ridx, nridx, flags);
    mlp_kernel<<<dim3((NITEM + 31) / 32), dim3(256), 0, stream>>>(vfeat, W1, b1, W2, b2, feat);
    contrast_kernel<<<dim3(BATCH), dim3(256), 0, stream>>>(user, item, flags, idemb, feat, rowvals);
    finalize_kernel<<<dim3(1), dim3(256), 0, stream>>>(rowvals, out);
}

// Round 2
// 143.454 us; speedup vs baseline: 2.0148x; 2.0148x over previous
//
#include <hip/hip_runtime.h>
#include <math.h>

#define NUSER 100000
#define NITEM 50000
#define DIM_E 128
#define DIM_F 256
#define BATCH 1024
#define NCOL 128            /* 1 + NUM_NEG */
#define FLAT (BATCH * NCOL)

typedef __attribute__((ext_vector_type(8))) short bf16x8;
typedef __attribute__((ext_vector_type(4))) short bf16x4;
typedef __attribute__((ext_vector_type(4))) float f32x4;

__device__ __forceinline__ float dot4(float4 a, float4 b) {
    return a.x * b.x + a.y * b.y + a.z * b.z + a.w * b.w;
}

__device__ __forceinline__ short f2bf(float x) {
    unsigned u = __float_as_uint(x);
    unsigned r = (u + 0x7FFFu + ((u >> 16) & 1u)) >> 16;
    return (short)r;
}

__global__ __launch_bounds__(256) void zero_flags_kernel(int* __restrict__ flags) {
    int i = blockIdx.x * 256 + threadIdx.x;
    if (i < FLAT) flags[i] = 0;
}

__global__ __launch_bounds__(256) void scatter_flags_kernel(const int* __restrict__ ridx,
                                                            int n, int* __restrict__ flags) {
    int i = blockIdx.x * 256 + threadIdx.x;
    if (i < n) flags[ridx[i]] = 1;
}

// Pre-transpose weights to bf16: w1t[n][k] = W1[k][n] (256x256), w2t[n][k] = W2[k][n] (128x256)
__global__ __launch_bounds__(256) void prep_kernel(const float* __restrict__ W1,
                                                   const float* __restrict__ W2,
                                                   short* __restrict__ w1t,
                                                   short* __restrict__ w2t) {
    int i = blockIdx.x * 256 + threadIdx.x;
    if (i < 256 * 256) {
        int n = i >> 8, k = i & 255;
        w1t[i] = f2bf(W1[(size_t)k * 256 + n]);
    } else if (i < 256 * 256 + 128 * 256) {
        int j = i - 256 * 256;
        int n = j >> 8, k = j & 255;
        w2t[j] = f2bf(W2[(size_t)k * 128 + n]);
    }
}

// Fused MLP via bf16 MFMA: feature = leaky(l2norm(v_feat) @ W1 + b1) @ W2 + b2
// 64 rows per block, 256 threads (4 waves). Wave w owns a 64-col (stage1) /
// 32-col (stage2) output panel across all 64 rows.
__global__ __launch_bounds__(256) void mlp_mfma_kernel(const float* __restrict__ vfeat,
                                                       const short* __restrict__ w1t,
                                                       const float* __restrict__ b1,
                                                       const short* __restrict__ w2t,
                                                       const float* __restrict__ b2,
                                                       float* __restrict__ featout) {
    // XOR-swizzled bf16 tiles: element (row, col) lives at row*256 + (col ^ ((row&7)<<3))
    __shared__ __align__(16) short As[64 * 256];
    __shared__ __align__(16) short Hs[64 * 256];
    const int t = threadIdx.x;
    const int w = t >> 6;       // wave 0..3
    const int l = t & 63;
    const int r0 = blockIdx.x * 64;
    const int fr = l & 15;      // fragment row/col index
    const int kg = l >> 4;      // k-group 0..3

    // ---- load v_feat tile, fold l2norm, convert to bf16, swizzled LDS write ----
    // wave w handles rows {i*4 + w}, lane = float4-column
#pragma unroll
    for (int i = 0; i < 16; ++i) {
        int row = i * 4 + w;
        int gr = r0 + row;
        float4 v = make_float4(0.f, 0.f, 0.f, 0.f);
        if (gr < NITEM) v = *(const float4*)(vfeat + (size_t)gr * DIM_F + l * 4);
        float s = dot4(v, v);
#pragma unroll
        for (int off = 32; off >= 1; off >>= 1) s += __shfl_xor(s, off);
        float inv = 1.f / fmaxf(sqrtf(s), 1e-12f);
        bf16x4 p;
        p[0] = f2bf(v.x * inv);
        p[1] = f2bf(v.y * inv);
        p[2] = f2bf(v.z * inv);
        p[3] = f2bf(v.w * inv);
        int sidx = row * 256 + ((l * 4) ^ ((row & 7) << 3));
        *(bf16x4*)(&As[sidx]) = p;
    }
    __syncthreads();

    // ---- stage 1: H = leaky(A @ W1T^T + b1), wave cols [w*64, w*64+64) ----
    {
        f32x4 acc[4][4];
#pragma unroll
        for (int rt = 0; rt < 4; ++rt)
#pragma unroll
            for (int ct = 0; ct < 4; ++ct) acc[rt][ct] = (f32x4){0.f, 0.f, 0.f, 0.f};

        float b1v[4];
#pragma unroll
        for (int ct = 0; ct < 4; ++ct) b1v[ct] = b1[w * 64 + ct * 16 + fr];

        for (int kc = 0; kc < 8; ++kc) {
            const int kb = kc * 32 + kg * 8;
            bf16x8 af[4];
#pragma unroll
            for (int rt = 0; rt < 4; ++rt) {
                int row = rt * 16 + fr;
                af[rt] = *(const bf16x8*)(&As[row * 256 + (kb ^ ((row & 7) << 3))]);
            }
#pragma unroll
            for (int ct = 0; ct < 4; ++ct) {
                int ncol = w * 64 + ct * 16 + fr;
                bf16x8 bfr = *(const bf16x8*)(w1t + (size_t)ncol * 256 + kb);
#pragma unroll
                for (int rt = 0; rt < 4; ++rt)
                    acc[rt][ct] = __builtin_amdgcn_mfma_f32_16x16x32_bf16(af[rt], bfr, acc[rt][ct], 0, 0, 0);
            }
        }
        // epilogue: bias + leaky_relu + bf16, write swizzled Hs
#pragma unroll
        for (int rt = 0; rt < 4; ++rt)
#pragma unroll
            for (int ct = 0; ct < 4; ++ct) {
                int colH = w * 64 + ct * 16 + fr;
#pragma unroll
                for (int r = 0; r < 4; ++r) {
                    float h = acc[rt][ct][r] + b1v[ct];
                    h = h > 0.f ? h : 0.01f * h;
                    int row = rt * 16 + kg * 4 + r;
                    Hs[row * 256 + (colH ^ ((row & 7) << 3))] = f2bf(h);
                }
            }
    }
    __syncthreads();

    // ---- stage 2: feature = H @ W2T^T + b2, wave cols [w*32, w*32+32) ----
    {
        f32x4 acc2[4][2];
#pragma unroll
        for (int rt = 0; rt < 4; ++rt)
#pragma unroll
            for (int ct = 0; ct < 2; ++ct) acc2[rt][ct] = (f32x4){0.f, 0.f, 0.f, 0.f};

        float b2v[2];
#pragma unroll
        for (int ct = 0; ct < 2; ++ct) b2v[ct] = b2[w * 32 + ct * 16 + fr];

        for (int kc = 0; kc < 8; ++kc) {
            const int kb = kc * 32 + kg * 8;
            bf16x8 hf[4];
#pragma unroll
            for (int rt = 0; rt < 4; ++rt) {
                int row = rt * 16 + fr;
                hf[rt] = *(const bf16x8*)(&Hs[row * 256 + (kb ^ ((row & 7) << 3))]);
            }
#pragma unroll
            for (int ct = 0; ct < 2; ++ct) {
                int ncol = w * 32 + ct * 16 + fr;
                bf16x8 bfr = *(const bf16x8*)(w2t + (size_t)ncol * 256 + kb);
#pragma unroll
                for (int rt = 0; rt < 4; ++rt)
                    acc2[rt][ct] = __builtin_amdgcn_mfma_f32_16x16x32_bf16(hf[rt], bfr, acc2[rt][ct], 0, 0, 0);
            }
        }
#pragma unroll
        for (int rt = 0; rt < 4; ++rt)
#pragma unroll
            for (int ct = 0; ct < 2; ++ct) {
                int col = w * 32 + ct * 16 + fr;
#pragma unroll
                for (int r = 0; r < 4; ++r) {
                    int row = r0 + rt * 16 + kg * 4 + r;
                    if (row < NITEM) featout[(size_t)row * DIM_E + col] = acc2[rt][ct][r] + b2v[ct];
                }
            }
    }
}

// One block per batch row (128 flat elements). 2 threads per element.
__global__ __launch_bounds__(256) void contrast_kernel(const int* __restrict__ user,
                                                       const int* __restrict__ item,
                                                       const int* __restrict__ flags,
                                                       const float* __restrict__ idemb,
                                                       const float* __restrict__ feat,
                                                       float* __restrict__ rowvals) {
    __shared__ float pe[128];           // normalized pos embedding
    __shared__ float s1s[128], s2s[128], rs[128];
    const int row = blockIdx.x;
    const int t = threadIdx.x;

    if (t < 32) {
        int p = item[(size_t)row * NCOL];  // item_tensor[row][0]
        float4 v = *(const float4*)(idemb + (size_t)p * DIM_E + t * 4);
        float s = dot4(v, v);
#pragma unroll
        for (int off = 16; off >= 1; off >>= 1) s += __shfl_xor(s, off, 32);
        float inv = 1.f / fmaxf(sqrtf(s), 1e-12f);
        *(float4*)(&pe[t * 4]) = make_float4(v.x * inv, v.y * inv, v.z * inv, v.w * inv);
    }
    __syncthreads();

    const int e = t >> 1;       // element 0..127
    const int h = t & 1;        // half of the 128-dim vector
    const size_t j = (size_t)row * NCOL + e;
    const int u = user[j];
    const int it = item[j];
    const int fl = flags[j];
    const float* up = idemb + (size_t)u * DIM_E + h * 64;
    const float* ip = idemb + (size_t)it * DIM_E + h * 64;
    const float* fp = feat + (size_t)(it - NUSER) * DIM_E + h * 64;

    float su = 0.f, si = 0.f, sf = 0.f, dpf = 0.f, dux = 0.f;
#pragma unroll
    for (int i = 0; i < 16; ++i) {
        float4 uv = ((const float4*)up)[i];
        float4 iv = ((const float4*)ip)[i];
        float4 fv = ((const float4*)fp)[i];
        float4 pv = *(const float4*)(&pe[h * 64 + i * 4]);
        su += dot4(uv, uv);
        si += dot4(iv, iv);
        sf += dot4(fv, fv);
        dpf += dot4(pv, fv);
        float4 xv = fl ? fv : iv;
        dux += dot4(uv, xv);
    }
    su += __shfl_xor(su, 1);
    si += __shfl_xor(si, 1);
    sf += __shfl_xor(sf, 1);
    dpf += __shfl_xor(dpf, 1);
    dux += __shfl_xor(dux, 1);

    if (h == 0) {
        float fnorm = fmaxf(sqrtf(sf), 1e-12f);
        float d1 = dpf / fnorm;                 // head_embed . head_feat
        s1s[e] = expf(d1 * 0.5f);               // / TEMP (=2)
        s2s[e] = expf(dux * 0.5f);
        rs[e] = sqrtf(su) + sqrtf(si);
    }
    __syncthreads();

    if (t < 64) {
        float a1 = s1s[t] + s1s[t + 64];
        float a2 = s2s[t] + s2s[t + 64];
        float a3 = rs[t] + rs[t + 64];
#pragma unroll
        for (int off = 32; off >= 1; off >>= 1) {
            a1 += __shfl_xor(a1, off);
            a2 += __shfl_xor(a2, off);
            a3 += __shfl_xor(a3, off);
        }
        if (t == 0) {
            rowvals[row * 4 + 0] = logf(a1) - logf(s1s[0]);
            rowvals[row * 4 + 1] = logf(a2) - logf(s2s[0]);
            rowvals[row * 4 + 2] = a3;
        }
    }
}

__global__ __launch_bounds__(256) void finalize_kernel(const float* __restrict__ rowvals,
                                                       float* __restrict__ out) {
    float c1 = 0.f, c2 = 0.f, rg = 0.f;
    for (int i = threadIdx.x; i < BATCH; i += 256) {
        c1 += rowvals[i * 4 + 0];
        c2 += rowvals[i * 4 + 1];
        rg += rowvals[i * 4 + 2];
    }
#pragma unroll
    for (int off = 32; off >= 1; off >>= 1) {
        c1 += __shfl_xor(c1, off);
        c2 += __shfl_xor(c2, off);
        rg += __shfl_xor(rg, off);
    }
    __shared__ float buf[4][3];
    int wid = threadIdx.x >> 6, lane = threadIdx.x & 63;
    if (lane == 0) { buf[wid][0] = c1; buf[wid][1] = c2; buf[wid][2] = rg; }
    __syncthreads();
    if (threadIdx.x == 0) {
        float C1 = buf[0][0] + buf[1][0] + buf[2][0] + buf[3][0];
        float C2 = buf[0][1] + buf[1][1] + buf[2][1] + buf[3][1];
        float R  = buf[0][2] + buf[1][2] + buf[2][2] + buf[3][2];
        out[0] = 0.5f * (C1 / (float)BATCH) + 0.5f * (C2 / (float)BATCH);
        out[1] = 0.5f * (R / (float)FLAT);
    }
}

extern "C" void kernel_launch(void* const* d_in, const int* in_sizes, int n_in,
                              void* d_out, int out_size, void* d_ws, size_t ws_size,
                              hipStream_t stream) {
    const int* user = (const int*)d_in[0];
    const int* item = (const int*)d_in[1];
    const int* ridx = (const int*)d_in[2];
    const float* idemb = (const float*)d_in[3];
    const float* vfeat = (const float*)d_in[4];
    const float* W1 = (const float*)d_in[5];
    const float* b1 = (const float*)d_in[6];
    const float* W2 = (const float*)d_in[7];
    const float* b2 = (const float*)d_in[8];
    float* out = (float*)d_out;

    char* ws = (char*)d_ws;
    float* feat = (float*)ws;                                   // 25,600,000 B
    int* flags = (int*)(ws + 25600000);                         // 524,288 B
    float* rowvals = (float*)(ws + 26124288);                   // 16,384 B
    short* w1t = (short*)(ws + 26140672);                       // 131,072 B
    short* w2t = (short*)(ws + 26271744);                       // 65,536 B

    const int nridx = in_sizes[2];

    prep_kernel<<<dim3(384), dim3(256), 0, stream>>>(W1, W2, w1t, w2t);
    zero_flags_kernel<<<dim3((FLAT + 255) / 256), dim3(256), 0, stream>>>(flags);
    scatter_flags_kernel<<<dim3((nridx + 255) / 256), dim3(256), 0, stream>>>(ridx, nridx, flags);
    mlp_mfma_kernel<<<dim3((NITEM + 63) / 64), dim3(256), 0, stream>>>(vfeat, w1t, b1, w2t, b2, feat);
    contrast_kernel<<<dim3(BATCH), dim3(256), 0, stream>>>(user, item, flags, idemb, feat, rowvals);
    finalize_kernel<<<dim3(1), dim3(256), 0, stream>>>(rowvals, out);
}

// Round 3
// 100.347 us; speedup vs baseline: 2.8804x; 1.4296x over previous
//
#include <hip/hip_runtime.h>
#include <math.h>

#define NUSER 100000
#define NITEM 50000
#define NID   (NUSER + NITEM)
#define DIM_E 128
#define DIM_F 256
#define BATCH 1024
#define NCOL 128            /* 1 + NUM_NEG */
#define FLAT (BATCH * NCOL)

typedef __attribute__((ext_vector_type(8))) short bf16x8;
typedef __attribute__((ext_vector_type(4))) short bf16x4;
typedef __attribute__((ext_vector_type(4))) float f32x4;

__device__ __forceinline__ float dot4(float4 a, float4 b) {
    return a.x * b.x + a.y * b.y + a.z * b.z + a.w * b.w;
}

__device__ __forceinline__ short f2bf(float x) {
    unsigned u = __float_as_uint(x);
    unsigned r = (u + 0x7FFFu + ((u >> 16) & 1u)) >> 16;
    return (short)r;
}

__device__ __forceinline__ float bf2f(short s) {
    return __uint_as_float(((unsigned)(unsigned short)s) << 16);
}

__global__ __launch_bounds__(256) void zero_flags_kernel(int* __restrict__ flags) {
    int i = blockIdx.x * 256 + threadIdx.x;
    if (i < FLAT) flags[i] = 0;
}

__global__ __launch_bounds__(256) void scatter_flags_kernel(const int* __restrict__ ridx,
                                                            int n, int* __restrict__ flags) {
    int i = blockIdx.x * 256 + threadIdx.x;
    if (i < n) flags[ridx[i]] = 1;
}

// Pre-transpose weights to bf16: w1t[n][k] = W1[k][n] (256x256), w2t[n][k] = W2[k][n] (128x256)
__global__ __launch_bounds__(256) void prep_kernel(const float* __restrict__ W1,
                                                   const float* __restrict__ W2,
                                                   short* __restrict__ w1t,
                                                   short* __restrict__ w2t) {
    int i = blockIdx.x * 256 + threadIdx.x;
    if (i < 256 * 256) {
        int n = i >> 8, k = i & 255;
        w1t[i] = f2bf(W1[(size_t)k * 256 + n]);
    } else if (i < 256 * 256 + 128 * 256) {
        int j = i - 256 * 256;
        int n = j >> 8, k = j & 255;
        w2t[j] = f2bf(W2[(size_t)k * 128 + n]);
    }
}

// Streaming: id_embedding fp32 -> bf16 copy + fp32 norm table.
// 32 lanes per row, float4 per lane.
__global__ __launch_bounds__(256) void conv_kernel(const float* __restrict__ idemb,
                                                   short* __restrict__ idemb_bf,
                                                   float* __restrict__ norms) {
    const int sub = threadIdx.x & 31;
    const int g0 = (blockIdx.x * 256 + threadIdx.x) >> 5;
    const int ng = gridDim.x * 8;
    for (int row = g0; row < NID; row += ng) {
        float4 v = *(const float4*)(idemb + (size_t)row * DIM_E + sub * 4);
        float s = dot4(v, v);
#pragma unroll
        for (int off = 16; off >= 1; off >>= 1) s += __shfl_xor(s, off);
        bf16x4 p;
        p[0] = f2bf(v.x); p[1] = f2bf(v.y); p[2] = f2bf(v.z); p[3] = f2bf(v.w);
        *(bf16x4*)(idemb_bf + (size_t)row * DIM_E + sub * 4) = p;
        if (sub == 0) norms[row] = sqrtf(s);
    }
}

// Fused MLP via bf16 MFMA: feature = leaky(l2norm(v_feat) @ W1 + b1) @ W2 + b2
// Output written directly in bf16.
__global__ __launch_bounds__(256) void mlp_mfma_kernel(const float* __restrict__ vfeat,
                                                       const short* __restrict__ w1t,
                                                       const float* __restrict__ b1,
                                                       const short* __restrict__ w2t,
                                                       const float* __restrict__ b2,
                                                       short* __restrict__ featout) {
    // XOR-swizzled bf16 tiles: element (row, col) lives at row*256 + (col ^ ((row&7)<<3))
    __shared__ __align__(16) short As[64 * 256];
    __shared__ __align__(16) short Hs[64 * 256];
    const int t = threadIdx.x;
    const int w = t >> 6;       // wave 0..3
    const int l = t & 63;
    const int r0 = blockIdx.x * 64;
    const int fr = l & 15;      // fragment row/col index
    const int kg = l >> 4;      // k-group 0..3

    // ---- load v_feat tile, fold l2norm, convert to bf16, swizzled LDS write ----
#pragma unroll
    for (int i = 0; i < 16; ++i) {
        int row = i * 4 + w;
        int gr = r0 + row;
        float4 v = make_float4(0.f, 0.f, 0.f, 0.f);
        if (gr < NITEM) v = *(const float4*)(vfeat + (size_t)gr * DIM_F + l * 4);
        float s = dot4(v, v);
#pragma unroll
        for (int off = 32; off >= 1; off >>= 1) s += __shfl_xor(s, off);
        float inv = 1.f / fmaxf(sqrtf(s), 1e-12f);
        bf16x4 p;
        p[0] = f2bf(v.x * inv);
        p[1] = f2bf(v.y * inv);
        p[2] = f2bf(v.z * inv);
        p[3] = f2bf(v.w * inv);
        int sidx = row * 256 + ((l * 4) ^ ((row & 7) << 3));
        *(bf16x4*)(&As[sidx]) = p;
    }
    __syncthreads();

    // ---- stage 1: H = leaky(A @ W1T^T + b1), wave cols [w*64, w*64+64) ----
    {
        f32x4 acc[4][4];
#pragma unroll
        for (int rt = 0; rt < 4; ++rt)
#pragma unroll
            for (int ct = 0; ct < 4; ++ct) acc[rt][ct] = (f32x4){0.f, 0.f, 0.f, 0.f};

        float b1v[4];
#pragma unroll
        for (int ct = 0; ct < 4; ++ct) b1v[ct] = b1[w * 64 + ct * 16 + fr];

        for (int kc = 0; kc < 8; ++kc) {
            const int kb = kc * 32 + kg * 8;
            bf16x8 af[4];
#pragma unroll
            for (int rt = 0; rt < 4; ++rt) {
                int row = rt * 16 + fr;
                af[rt] = *(const bf16x8*)(&As[row * 256 + (kb ^ ((row & 7) << 3))]);
            }
#pragma unroll
            for (int ct = 0; ct < 4; ++ct) {
                int ncol = w * 64 + ct * 16 + fr;
                bf16x8 bfr = *(const bf16x8*)(w1t + (size_t)ncol * 256 + kb);
#pragma unroll
                for (int rt = 0; rt < 4; ++rt)
                    acc[rt][ct] = __builtin_amdgcn_mfma_f32_16x16x32_bf16(af[rt], bfr, acc[rt][ct], 0, 0, 0);
            }
        }
#pragma unroll
        for (int rt = 0; rt < 4; ++rt)
#pragma unroll
            for (int ct = 0; ct < 4; ++ct) {
                int colH = w * 64 + ct * 16 + fr;
#pragma unroll
                for (int r = 0; r < 4; ++r) {
                    float h = acc[rt][ct][r] + b1v[ct];
                    h = h > 0.f ? h : 0.01f * h;
                    int row = rt * 16 + kg * 4 + r;
                    Hs[row * 256 + (colH ^ ((row & 7) << 3))] = f2bf(h);
                }
            }
    }
    __syncthreads();

    // ---- stage 2: feature = H @ W2T^T + b2, wave cols [w*32, w*32+32) ----
    {
        f32x4 acc2[4][2];
#pragma unroll
        for (int rt = 0; rt < 4; ++rt)
#pragma unroll
            for (int ct = 0; ct < 2; ++ct) acc2[rt][ct] = (f32x4){0.f, 0.f, 0.f, 0.f};

        float b2v[2];
#pragma unroll
        for (int ct = 0; ct < 2; ++ct) b2v[ct] = b2[w * 32 + ct * 16 + fr];

        for (int kc = 0; kc < 8; ++kc) {
            const int kb = kc * 32 + kg * 8;
            bf16x8 hf[4];
#pragma unroll
            for (int rt = 0; rt < 4; ++rt) {
                int row = rt * 16 + fr;
                hf[rt] = *(const bf16x8*)(&Hs[row * 256 + (kb ^ ((row & 7) << 3))]);
            }
#pragma unroll
            for (int ct = 0; ct < 2; ++ct) {
                int ncol = w * 32 + ct * 16 + fr;
                bf16x8 bfr = *(const bf16x8*)(w2t + (size_t)ncol * 256 + kb);
#pragma unroll
                for (int rt = 0; rt < 4; ++rt)
                    acc2[rt][ct] = __builtin_amdgcn_mfma_f32_16x16x32_bf16(hf[rt], bfr, acc2[rt][ct], 0, 0, 0);
            }
        }
#pragma unroll
        for (int rt = 0; rt < 4; ++rt)
#pragma unroll
            for (int ct = 0; ct < 2; ++ct) {
                int col = w * 32 + ct * 16 + fr;
#pragma unroll
                for (int r = 0; r < 4; ++r) {
                    int row = r0 + rt * 16 + kg * 4 + r;
                    if (row < NITEM) featout[(size_t)row * DIM_E + col] = f2bf(acc2[rt][ct][r] + b2v[ct]);
                }
            }
    }
}

// One block per batch row (128 flat elements). 2 threads per element, bf16 gathers.
__global__ __launch_bounds__(256) void contrast_kernel(const int* __restrict__ user,
                                                       const int* __restrict__ item,
                                                       const int* __restrict__ flags,
                                                       const float* __restrict__ idemb,
                                                       const short* __restrict__ idemb_bf,
                                                       const float* __restrict__ norms,
                                                       const short* __restrict__ feat,
                                                       float* __restrict__ rowvals) {
    __shared__ float pe[128];           // normalized pos embedding (fp32)
    __shared__ float s1s[128], s2s[128], rs[128];
    const int row = blockIdx.x;
    const int t = threadIdx.x;

    if (t < 32) {
        int p = item[(size_t)row * NCOL];  // item_tensor[row][0]
        float4 v = *(const float4*)(idemb + (size_t)p * DIM_E + t * 4);
        float s = dot4(v, v);
#pragma unroll
        for (int off = 16; off >= 1; off >>= 1) s += __shfl_xor(s, off);
        float inv = 1.f / fmaxf(sqrtf(s), 1e-12f);
        *(float4*)(&pe[t * 4]) = make_float4(v.x * inv, v.y * inv, v.z * inv, v.w * inv);
    }
    __syncthreads();

    const int e = t >> 1;       // element 0..127
    const int h = t & 1;        // half of the 128-dim vector
    const size_t j = (size_t)row * NCOL + e;
    const int u = user[j];
    const int it = item[j];
    const int fl = flags[j];
    const short* up = idemb_bf + (size_t)u * DIM_E + h * 64;
    const short* ip = idemb_bf + (size_t)it * DIM_E + h * 64;
    const short* fp = feat + (size_t)(it - NUSER) * DIM_E + h * 64;

    bf16x8 ub[8], fb[8], xb[8];
#pragma unroll
    for (int i = 0; i < 8; ++i) { ub[i] = ((const bf16x8*)up)[i]; fb[i] = ((const bf16x8*)fp)[i]; }
    if (fl) {
#pragma unroll
        for (int i = 0; i < 8; ++i) xb[i] = fb[i];
    } else {
#pragma unroll
        for (int i = 0; i < 8; ++i) xb[i] = ((const bf16x8*)ip)[i];
    }
    float nu = norms[u];
    float ni = norms[it];

    float sf = 0.f, dpf = 0.f, dux = 0.f;
#pragma unroll
    for (int i = 0; i < 8; ++i) {
        float4 p0 = *(const float4*)(&pe[h * 64 + i * 8]);
        float4 p1 = *(const float4*)(&pe[h * 64 + i * 8 + 4]);
        float pk[8] = {p0.x, p0.y, p0.z, p0.w, p1.x, p1.y, p1.z, p1.w};
#pragma unroll
        for (int k = 0; k < 8; ++k) {
            float fv = bf2f(fb[i][k]);
            float uv = bf2f(ub[i][k]);
            float xv = bf2f(xb[i][k]);
            sf += fv * fv;
            dpf += pk[k] * fv;
            dux += uv * xv;
        }
    }
    sf += __shfl_xor(sf, 1);
    dpf += __shfl_xor(dpf, 1);
    dux += __shfl_xor(dux, 1);

    if (h == 0) {
        float fnorm = fmaxf(sqrtf(sf), 1e-12f);
        s1s[e] = expf(dpf / fnorm * 0.5f);      // / TEMP (=2)
        s2s[e] = expf(dux * 0.5f);
        rs[e] = nu + ni;
    }
    __syncthreads();

    if (t < 64) {
        float a1 = s1s[t] + s1s[t + 64];
        float a2 = s2s[t] + s2s[t + 64];
        float a3 = rs[t] + rs[t + 64];
#pragma unroll
        for (int off = 32; off >= 1; off >>= 1) {
            a1 += __shfl_xor(a1, off);
            a2 += __shfl_xor(a2, off);
            a3 += __shfl_xor(a3, off);
        }
        if (t == 0) {
            rowvals[row * 4 + 0] = logf(a1) - logf(s1s[0]);
            rowvals[row * 4 + 1] = logf(a2) - logf(s2s[0]);
            rowvals[row * 4 + 2] = a3;
        }
    }
}

__global__ __launch_bounds__(256) void finalize_kernel(const float* __restrict__ rowvals,
                                                       float* __restrict__ out) {
    float c1 = 0.f, c2 = 0.f, rg = 0.f;
    for (int i = threadIdx.x; i < BATCH; i += 256) {
        c1 += rowvals[i * 4 + 0];
        c2 += rowvals[i * 4 + 1];
        rg += rowvals[i * 4 + 2];
    }
#pragma unroll
    for (int off = 32; off >= 1; off >>= 1) {
        c1 += __shfl_xor(c1, off);
        c2 += __shfl_xor(c2, off);
        rg += __shfl_xor(rg, off);
    }
    __shared__ float buf[4][3];
    int wid = threadIdx.x >> 6, lane = threadIdx.x & 63;
    if (lane == 0) { buf[wid][0] = c1; buf[wid][1] = c2; buf[wid][2] = rg; }
    __syncthreads();
    if (threadIdx.x == 0) {
        float C1 = buf[0][0] + buf[1][0] + buf[2][0] + buf[3][0];
        float C2 = buf[0][1] + buf[1][1] + buf[2][1] + buf[3][1];
        float R  = buf[0][2] + buf[1][2] + buf[2][2] + buf[3][2];
        out[0] = 0.5f * (C1 / (float)BATCH) + 0.5f * (C2 / (float)BATCH);
        out[1] = 0.5f * (R / (float)FLAT);
    }
}

extern "C" void kernel_launch(void* const* d_in, const int* in_sizes, int n_in,
                              void* d_out, int out_size, void* d_ws, size_t ws_size,
                              hipStream_t stream) {
    const int* user = (const int*)d_in[0];
    const int* item = (const int*)d_in[1];
    const int* ridx = (const int*)d_in[2];
    const float* idemb = (const float*)d_in[3];
    const float* vfeat = (const float*)d_in[4];
    const float* W1 = (const float*)d_in[5];
    const float* b1 = (const float*)d_in[6];
    const float* W2 = (const float*)d_in[7];
    const float* b2 = (const float*)d_in[8];
    float* out = (float*)d_out;

    char* ws = (char*)d_ws;
    short* feat_bf  = (short*)(ws);                     // 12,800,000 B
    short* idemb_bf = (short*)(ws + 12800000);          // 38,400,000 B
    float* norms    = (float*)(ws + 51200000);          //    600,000 B
    int*   flags    = (int*)  (ws + 51800000);          //    524,288 B
    float* rowvals  = (float*)(ws + 52324288);          //     16,384 B
    short* w1t      = (short*)(ws + 52340672);          //    131,072 B
    short* w2t      = (short*)(ws + 52471744);          //     65,536 B  (end: 52,537,280)

    const int nridx = in_sizes[2];

    conv_kernel<<<dim3(2048), dim3(256), 0, stream>>>(idemb, idemb_bf, norms);
    prep_kernel<<<dim3(384), dim3(256), 0, stream>>>(W1, W2, w1t, w2t);
    zero_flags_kernel<<<dim3((FLAT + 255) / 256), dim3(256), 0, stream>>>(flags);
    scatter_flags_kernel<<<dim3((nridx + 255) / 256), dim3(256), 0, stream>>>(ridx, nridx, flags);
    mlp_mfma_kernel<<<dim3((NITEM + 63) / 64), dim3(256), 0, stream>>>(vfeat, w1t, b1, w2t, b2, feat_bf);
    contrast_kernel<<<dim3(BATCH), dim3(256), 0, stream>>>(user, item, flags, idemb, idemb_bf, norms, feat_bf, rowvals);
    finalize_kernel<<<dim3(1), dim3(256), 0, stream>>>(rowvals, out);
}